// Round 5
// baseline (350.205 us; speedup 1.0000x reference)
//
#include <hip/hip_runtime.h>

// YOLO loss on MI355X. Layout:
//   prediction: (N, S, S, 90)  fp32, N=8192, S=7  -> 401408 cells x 90 ch
//   target:     (N, S, S, 85)  fp32               -> 401408 cells x 85 ch
// Output: 6 fp32 scalars.
//
// R5: R3<->R4 A/B showed global_load_lds (cold HBM, shallow DMA queue) caps
// at ~1 TB/s, while plain vector loads sustained 2.5 TB/s even with a
// scratch-spill tax. So: stage with float4 loads -> 6 regs/thread (24 VGPR,
// no spill) -> ds_write, software-pipelined over 32-cell subtiles,
// double-buffered (2 x 22.4 KB LDS -> 3 blocks/CU):
//   iter s: issue loads(s+1) | compute(s) from LDS | ds_write(s+1) | barrier
// The vmcnt wait sits before the ds_writes, AFTER compute -> load latency is
// hidden by compute + 12 resident waves. One barrier per subtile.
// Work split per subtile: thread = (cell = tid&31, grp = tid>>5);
//   all threads: 10 class channels; grp0 threads also box/conf for their cell.
// 1568 blocks x 8 subtiles x 32 cells = 401408 cells exactly.

#define NCELLS (8192 * 49)
#define SUB 32                         // cells per subtile
#define SPB 8                          // subtiles per block
#define NBLOCKS (NCELLS / (SUB * SPB)) // 1568
#define TGT_F4 (SUB * 85 / 4)          // 680 float4 per subtile
#define PRED_F4 (SUB * 90 / 4)         // 720 float4 per subtile
constexpr float BSF = 8192.0f;

__device__ __forceinline__ void rel2abs(float x, float y, float w, float h,
                                        float fi, float fj,
                                        float& x1, float& y1, float& x2, float& y2) {
    float xc = (x + fj) / 7.0f;
    float yc = (y + fi) / 7.0f;
    float hw = w * 0.5f, hh = h * 0.5f;
    x1 = xc - hw; y1 = yc - hh; x2 = xc + hw; y2 = yc + hh;
}

__device__ __forceinline__ float iou_abs(float ax1, float ay1, float ax2, float ay2,
                                         float bx1, float by1, float bx2, float by2) {
    float iw = fminf(ax2, bx2) - fmaxf(ax1, bx1); iw = fmaxf(iw, 0.0f);
    float ih = fminf(ay2, by2) - fmaxf(ay1, by1); ih = fmaxf(ih, 0.0f);
    float inter  = iw * ih;
    float area_a = (ax2 - ax1) * (ay2 - ay1);
    float area_b = (bx2 - bx1) * (by2 - by1);
    return inter / (area_a + area_b - inter + 1e-6f);
}

__global__ __launch_bounds__(256) void yolo_main(const float* __restrict__ pred,
                                                 const float* __restrict__ tgt,
                                                 float* __restrict__ acc) {
    __shared__ __align__(16) float t_s[2][SUB * 85];   // 2 x 10880 B
    __shared__ __align__(16) float p_s[2][SUB * 90];   // 2 x 11520 B
    __shared__ float smr[4 * 5];

    const int tid   = threadIdx.x;
    const int lane  = tid & 63;
    const int wid   = tid >> 6;
    const int cell32 = tid & 31;       // cell within subtile
    const int grp    = tid >> 5;       // channel group 0..7

    const int blockStart = blockIdx.x * (SUB * SPB);

    float a_xy = 0.f, a_wh = 0.f, a_co = 0.f, a_cn = 0.f, a_cl = 0.f;

    float4 rt0, rt1, rt2, rp0, rp1, rp2;

    // ---- prologue: load + write subtile 0 into buf 0 ----
    {
        const float4* gt4 = (const float4*)(tgt  + (size_t)blockStart * 85);
        const float4* gp4 = (const float4*)(pred + (size_t)blockStart * 90);
        rt0 = gt4[tid]; rt1 = gt4[tid + 256];
        if (tid < TGT_F4 - 512)  rt2 = gt4[tid + 512];   // 168 threads
        rp0 = gp4[tid]; rp1 = gp4[tid + 256];
        if (tid < PRED_F4 - 512) rp2 = gp4[tid + 512];   // 208 threads
        float4* st4 = (float4*)t_s[0];
        float4* sp4 = (float4*)p_s[0];
        st4[tid] = rt0; st4[tid + 256] = rt1;
        if (tid < TGT_F4 - 512)  st4[tid + 512] = rt2;
        sp4[tid] = rp0; sp4[tid + 256] = rp1;
        if (tid < PRED_F4 - 512) sp4[tid + 512] = rp2;
    }
    __syncthreads();

    #pragma unroll 2
    for (int s = 0; s < SPB; ++s) {
        // ---- issue next subtile's global loads (in flight across compute) ----
        if (s < SPB - 1) {
            const int nbase = blockStart + (s + 1) * SUB;
            const float4* gt4 = (const float4*)(tgt  + (size_t)nbase * 85);
            const float4* gp4 = (const float4*)(pred + (size_t)nbase * 90);
            rt0 = gt4[tid]; rt1 = gt4[tid + 256];
            if (tid < TGT_F4 - 512)  rt2 = gt4[tid + 512];
            rp0 = gp4[tid]; rp1 = gp4[tid + 256];
            if (tid < PRED_F4 - 512) rp2 = gp4[tid + 512];
        }

        // ---- compute current subtile from LDS ----
        const float* tr = &t_s[s & 1][85 * cell32];
        const float* pr = &p_s[s & 1][90 * cell32];

        float tc   = tr[4];
        float objf = (tc != 0.0f) ? 1.0f : 0.0f;

        // class SSE: this thread's 10 channels of its cell
        {
            const int c0 = grp * 10;
            float sse = 0.f;
            #pragma unroll
            for (int ch = 0; ch < 10; ++ch) {
                float d = tr[5 + c0 + ch] - pr[10 + c0 + ch];
                sse += d * d;
            }
            a_cl += objf * sse;
        }

        // box + conf: grp 0 threads only (one per cell)
        if (grp == 0) {
            float tx = tr[0], ty = tr[1], tw = tr[2], th = tr[3];
            float p0x = pr[0], p0y = pr[1], p0w = pr[2], p0h = pr[3];
            float p1x = pr[5], p1y = pr[6], p1w = pr[7], p1h = pr[8];
            float pc  = pr[9];                 // pred_c = prediction[..., 9]

            int cell = blockStart + s * SUB + cell32;
            int sij  = cell % 49;
            float fi = (float)(sij / 7);
            float fj = (float)(sij % 7);

            float t1, t2, t3, t4, a1, a2, a3, a4, b1, b2, b3, b4;
            rel2abs(tx,  ty,  tw,  th,  fi, fj, t1, t2, t3, t4);
            rel2abs(p0x, p0y, p0w, p0h, fi, fj, a1, a2, a3, a4);
            rel2abs(p1x, p1y, p1w, p1h, fi, fj, b1, b2, b3, b4);

            float iou0 = iou_abs(t1, t2, t3, t4, a1, a2, a3, a4);
            float iou1 = iou_abs(t1, t2, t3, t4, b1, b2, b3, b4);

            bool sel = iou0 > iou1;   // ref: where(iou0>iou1, pred[5:10], pred[0:5])
            float xh = sel ? p1x : p0x;
            float yh = sel ? p1y : p0y;
            float wh = sel ? p1w : p0w;
            float hh = sel ? p1h : p0h;

            float dx = tx - xh, dy = ty - yh;
            a_xy += objf * (dx * dx + dy * dy);

            float sw = sqrtf(tw) - sqrtf(fmaxf(wh, 0.0f));
            float sh = sqrtf(th) - sqrtf(fmaxf(hh, 0.0f));
            a_wh += objf * (sw * sw + sh * sh);

            float ce = tc - pc; ce *= ce;
            a_co += objf * ce;
            a_cn += (1.0f - objf) * ce;
        }

        // ---- write next subtile into the other buffer, then barrier ----
        if (s < SPB - 1) {
            float4* st4 = (float4*)t_s[(s + 1) & 1];
            float4* sp4 = (float4*)p_s[(s + 1) & 1];
            st4[tid] = rt0; st4[tid + 256] = rt1;
            if (tid < TGT_F4 - 512)  st4[tid + 512] = rt2;
            sp4[tid] = rp0; sp4[tid + 256] = rp1;
            if (tid < PRED_F4 - 512) sp4[tid + 512] = rp2;
            __syncthreads();
        }
    }

    // ---------- reduce: wave shfl -> LDS -> block atomics ----------
    #pragma unroll
    for (int off = 32; off; off >>= 1) {
        a_xy += __shfl_down(a_xy, off, 64);
        a_wh += __shfl_down(a_wh, off, 64);
        a_co += __shfl_down(a_co, off, 64);
        a_cn += __shfl_down(a_cn, off, 64);
        a_cl += __shfl_down(a_cl, off, 64);
    }
    if (lane == 0) {
        smr[wid * 5 + 0] = a_xy; smr[wid * 5 + 1] = a_wh; smr[wid * 5 + 2] = a_co;
        smr[wid * 5 + 3] = a_cn; smr[wid * 5 + 4] = a_cl;
    }
    __syncthreads();
    if (tid == 0) {
        float s0 = 0.f, s1 = 0.f, s2 = 0.f, s3 = 0.f, s4 = 0.f;
        #pragma unroll
        for (int w = 0; w < 4; ++w) {
            s0 += smr[w * 5 + 0]; s1 += smr[w * 5 + 1]; s2 += smr[w * 5 + 2];
            s3 += smr[w * 5 + 3]; s4 += smr[w * 5 + 4];
        }
        atomicAdd(&acc[0], s0);
        atomicAdd(&acc[1], s1);
        atomicAdd(&acc[2], s2);
        atomicAdd(&acc[3], s3);
        atomicAdd(&acc[4], s4);
    }
}

__global__ void yolo_finalize(const float* __restrict__ acc, float* __restrict__ out) {
    if (threadIdx.x == 0 && blockIdx.x == 0) {
        float lxy = acc[0] / BSF;
        float lwh = acc[1] / BSF;
        float lco = acc[2] / BSF;
        float lcn = acc[3] / BSF;
        float lcl = acc[4] / BSF;
        out[0] = (5.0f * lxy + 5.0f * lwh + lco + 0.5f * lcn + lcl) / BSF;
        out[1] = lxy;
        out[2] = lwh;
        out[3] = lco;
        out[4] = lcn;
        out[5] = lcl;
    }
}

extern "C" void kernel_launch(void* const* d_in, const int* in_sizes, int n_in,
                              void* d_out, int out_size, void* d_ws, size_t ws_size,
                              hipStream_t stream) {
    const float* pred = (const float*)d_in[0];
    const float* tgt  = (const float*)d_in[1];
    float* out = (float*)d_out;
    float* acc = (float*)d_ws;   // 5 fp32 accumulators

    // d_ws is poisoned (0xAA) before every timed launch -> must zero here.
    hipMemsetAsync(acc, 0, 5 * sizeof(float), stream);

    yolo_main<<<NBLOCKS, 256, 0, stream>>>(pred, tgt, acc);
    yolo_finalize<<<1, 64, 0, stream>>>(acc, out);
}